// Round 7
// baseline (264.714 us; speedup 1.0000x reference)
//
#include <hip/hip_runtime.h>
#include <hip/hip_bf16.h>
#include <cstdint>

// GCN layer: y = relu(dnorm_n * (adj @ (dnorm_m * x @ W)) + b)
// B=128, N=512, F_IN=F_OUT=128, fp32 in/out. bf16 MFMA internally.
//
// v8: split structure + m97-pattern agg GEMM.
//   k_prep    : Wt[g][k] = bf16(W[k][g])                       (proven)
//   k_degcvt  : one pass adj fp32 -> dnorm + adjb bf16         (proven, v4)
//   k_xw      : h1t[b][g][m] = bf16(dnorm_m * (x@W))           (proven, r0)
//   k_agg_lds : out = relu(Dn*(adjb@h1t^T)+b); BOTH operands staged via
//               global_load_lds width=16 into LINEAR LDS (no VALU, no
//               VGPR round-trip) -- the documented 546->911 TF lever.
// Numerics bit-identical to r0/v4 (same values, same MFMA order).

#define BATCH 128
#define NN    512
#define FIN   128
#define FOUT  128

typedef unsigned short u16;
typedef __attribute__((ext_vector_type(8))) __bf16 bfrag;   // 8 bf16 = 4 VGPRs
typedef __attribute__((ext_vector_type(4))) float  f32x4;

#if __has_builtin(__builtin_amdgcn_global_load_lds)
#define HAS_GLOAD 1
#else
#define HAS_GLOAD 0
#endif

__device__ __forceinline__ u16 f2bf(float f) {
    uint32_t u = __builtin_bit_cast(uint32_t, f);
    u += 0x7fffu + ((u >> 16) & 1u);          // round-nearest-even
    return (u16)(u >> 16);
}
__device__ __forceinline__ ushort4 f2bf4(float4 v) {
    ushort4 r;
    r.x = f2bf(v.x); r.y = f2bf(v.y); r.z = f2bf(v.z); r.w = f2bf(v.w);
    return r;
}

#if HAS_GLOAD
__device__ __forceinline__ void gload16(const u16* g, u16* l) {
    __builtin_amdgcn_global_load_lds(
        (const __attribute__((address_space(1))) void*)(const void*)g,
        (__attribute__((address_space(3))) void*)(void*)l,
        16, 0, 0);
}
#endif

// ---------------- k_prep: Wt[g][k] = bf16(W[k][g]) --------------------------
__global__ __launch_bounds__(256) void k_prep(const float* __restrict__ W,
                                              u16* __restrict__ Wt) {
    int idx = blockIdx.x * 256 + threadIdx.x;   // grid 64 -> 16384 elements
    int g = idx >> 7, k = idx & 127;
    Wt[idx] = f2bf(W[k * FOUT + g]);
}

// ---------------- k_deg: dnorm[row] = rsqrt(rowsum(adj)) (fallback) ---------
__global__ __launch_bounds__(256) void k_deg(const float* __restrict__ adj,
                                             float* __restrict__ dnorm) {
    int wave = threadIdx.x >> 6;
    int lane = threadIdx.x & 63;
    int row  = (blockIdx.x << 2) + wave;          // [0, B*N)
    const float4* p = (const float4*)(adj + (size_t)row * NN);
    float4 v0 = p[lane];
    float4 v1 = p[lane + 64];
    float s = v0.x + v0.y + v0.z + v0.w + v1.x + v1.y + v1.z + v1.w;
    #pragma unroll
    for (int off = 32; off > 0; off >>= 1) s += __shfl_down(s, off, 64);
    if (lane == 0) dnorm[row] = (s > 0.f) ? rsqrtf(s) : 0.f;
}

// ---------------- k_degcvt: dnorm + adjb = bf16(adj) in one pass ------------
__global__ __launch_bounds__(256) void k_degcvt(const float* __restrict__ adj,
                                                u16* __restrict__ adjb,
                                                float* __restrict__ dnorm) {
    int wave = threadIdx.x >> 6;
    int lane = threadIdx.x & 63;
    int row  = (blockIdx.x << 2) + wave;          // [0, B*N)
    const float4* p = (const float4*)(adj + (size_t)row * NN);
    float4 v0 = p[lane];
    float4 v1 = p[lane + 64];
    u16* ob = adjb + (size_t)row * NN;
    *(ushort4*)(ob + (lane << 2))       = f2bf4(v0);   // elems 0..255
    *(ushort4*)(ob + (lane << 2) + 256) = f2bf4(v1);   // elems 256..511
    float s = v0.x + v0.y + v0.z + v0.w + v1.x + v1.y + v1.z + v1.w;
    #pragma unroll
    for (int off = 32; off > 0; off >>= 1) s += __shfl_down(s, off, 64);
    if (lane == 0) dnorm[row] = (s > 0.f) ? rsqrtf(s) : 0.f;
}

// ---------------- k_xw: h1t[b][g][m] = bf16(dnorm[bm] * (x @ W)[bm][g]) -----
// r0-proven: 128-row tile x 128 cols; 4 waves, each 4x4 of 16x16x32 MFMA
__global__ __launch_bounds__(256) void k_xw(const float* __restrict__ x,
                                            const u16* __restrict__ Wt,
                                            const float* __restrict__ dnorm,
                                            u16* __restrict__ h1t) {
    __shared__ u16 As[128][40];   // As[m][k] bf16, row pad to 40 (80 B)
    __shared__ u16 Bs[128][40];   // Bs[g][k] bf16 (Wt is already [g][k])
    __shared__ float sDn[128];

    int tid  = threadIdx.x;
    int row0 = blockIdx.x * 128;                 // global node-row base
    int wave = tid >> 6, lane = tid & 63;
    int wr = wave >> 1, wc = wave & 1;
    int q = lane >> 4, l16 = lane & 15;

    if (tid < 128) sDn[tid] = dnorm[row0 + tid];

    f32x4 acc[4][4];
    #pragma unroll
    for (int i = 0; i < 4; i++)
        #pragma unroll
        for (int j = 0; j < 4; j++) acc[i][j] = (f32x4)(0.f);

    for (int kt = 0; kt < FIN; kt += 32) {
        // stage A: x fp32 -> bf16 (128 m-rows x 32 k)
        #pragma unroll
        for (int j = 0; j < 4; j++) {
            int linear = tid + j * 256;          // 0..1023 float4 slots
            int m = linear >> 3, k4 = (linear & 7) << 2;
            float4 v = *(const float4*)(x + (size_t)(row0 + m) * FIN + kt + k4);
            *(ushort4*)&As[m][k4] = f2bf4(v);
        }
        // stage B: Wt bf16, 128 g-rows x 32 k = 512 uint4 slots (4 per row)
        #pragma unroll
        for (int j = 0; j < 2; j++) {
            int linear = tid + j * 256;          // 0..511
            int g = linear >> 2, k8 = (linear & 3) << 3;
            *(uint4*)&Bs[g][k8] = *(const uint4*)(Wt + (size_t)g * FIN + kt + k8);
        }
        __syncthreads();
        bfrag aF[4], bF[4];
        #pragma unroll
        for (int i = 0; i < 4; i++) aF[i] = *(const bfrag*)&As[wr * 64 + i * 16 + l16][q * 8];
        #pragma unroll
        for (int j = 0; j < 4; j++) bF[j] = *(const bfrag*)&Bs[wc * 64 + j * 16 + l16][q * 8];
        #pragma unroll
        for (int i = 0; i < 4; i++)
            #pragma unroll
            for (int j = 0; j < 4; j++)
                acc[i][j] = __builtin_amdgcn_mfma_f32_16x16x32_bf16(aF[i], bF[j], acc[i][j], 0, 0, 0);
        __syncthreads();
    }

    // epilogue: scale rows by dnorm, store transposed bf16
    int bb = row0 >> 9;                  // batch
    int mb = row0 & 511;                 // node base within batch
    #pragma unroll
    for (int i = 0; i < 4; i++) {
        int mloc = wr * 64 + i * 16 + q * 4;
        float d0 = sDn[mloc], d1 = sDn[mloc + 1], d2 = sDn[mloc + 2], d3 = sDn[mloc + 3];
        #pragma unroll
        for (int j = 0; j < 4; j++) {
            int g = wc * 64 + j * 16 + l16;
            f32x4 c = acc[i][j];
            ushort4 v;
            v.x = f2bf(c[0] * d0); v.y = f2bf(c[1] * d1);
            v.z = f2bf(c[2] * d2); v.w = f2bf(c[3] * d3);
            *(ushort4*)(h1t + ((size_t)bb * FOUT + g) * NN + mb + mloc) = v;
        }
    }
}

// ---------------- k_agg_lds: m97-pattern agg GEMM ---------------------------
// 128x128 tile per (n-tile, batch) block. LINEAR LDS tiles (no pad), both
// operands staged via global_load_lds width=16: per wave 2 slices per operand,
// slice s = wave*2+c covers u16 idx [s*512, s*512+512) of the 128x32 tile:
// lane writes LDS bytes (s*1024 + lane*16) <- global row r = idx>>5, col idx&31.
__global__ __launch_bounds__(256) void k_agg_lds(const u16* __restrict__ adjb,
                                                 const u16* __restrict__ h1t,
                                                 const float* __restrict__ dnorm,
                                                 const float* __restrict__ bias,
                                                 float* __restrict__ out) {
    __shared__ u16 As[128][32];   // As[n][k], linear (global_load_lds dest)
    __shared__ u16 Bs[128][32];   // Bs[g][k], linear
    __shared__ float sDn[128];
    __shared__ float sBias[128];

    int tid = threadIdx.x;
    int b   = blockIdx.y;
    int n0  = blockIdx.x * 128;
    int wave = tid >> 6, lane = tid & 63;
    int wr = wave >> 1, wc = wave & 1;
    int q = lane >> 4, l16 = lane & 15;

    const u16* Ab = adjb + ((size_t)b * NN + n0) * NN;
    const u16* Bm = h1t + (size_t)b * FOUT * NN;
    if (tid < 128) { sDn[tid] = dnorm[(size_t)b * NN + n0 + tid]; sBias[tid] = bias[tid]; }

    // per-lane slice coords (constant across K-loop)
    int s0   = wave * 2;                  // this wave's first slice
    int idx0 = s0 * 512 + lane * 8;       // u16 index in 128x32 tile
    int r0   = idx0 >> 5, c0 = idx0 & 31;
    int idx1 = idx0 + 512;
    int r1   = idx1 >> 5, c1 = idx1 & 31;

    f32x4 acc[4][4];
    #pragma unroll
    for (int i = 0; i < 4; i++)
        #pragma unroll
        for (int j = 0; j < 4; j++) acc[i][j] = (f32x4)(0.f);

    for (int kt = 0; kt < NN; kt += 32) {
#if HAS_GLOAD
        gload16(Ab + (size_t)r0 * NN + kt + c0, &As[0][0] + (size_t)s0 * 512);
        gload16(Ab + (size_t)r1 * NN + kt + c1, &As[0][0] + (size_t)(s0 + 1) * 512);
        gload16(Bm + (size_t)r0 * NN + kt + c0, &Bs[0][0] + (size_t)s0 * 512);
        gload16(Bm + (size_t)r1 * NN + kt + c1, &Bs[0][0] + (size_t)(s0 + 1) * 512);
#else
        *(uint4*)(&As[0][0] + (size_t)s0 * 512 + lane * 8) = *(const uint4*)(Ab + (size_t)r0 * NN + kt + c0);
        *(uint4*)(&As[0][0] + (size_t)(s0 + 1) * 512 + lane * 8) = *(const uint4*)(Ab + (size_t)r1 * NN + kt + c1);
        *(uint4*)(&Bs[0][0] + (size_t)s0 * 512 + lane * 8) = *(const uint4*)(Bm + (size_t)r0 * NN + kt + c0);
        *(uint4*)(&Bs[0][0] + (size_t)(s0 + 1) * 512 + lane * 8) = *(const uint4*)(Bm + (size_t)r1 * NN + kt + c1);
#endif
        __syncthreads();
        bfrag aF[4], bF[4];
        #pragma unroll
        for (int i = 0; i < 4; i++) aF[i] = *(const bfrag*)&As[wr * 64 + i * 16 + l16][q * 8];
        #pragma unroll
        for (int j = 0; j < 4; j++) bF[j] = *(const bfrag*)&Bs[wc * 64 + j * 16 + l16][q * 8];
        #pragma unroll
        for (int i = 0; i < 4; i++)
            #pragma unroll
            for (int j = 0; j < 4; j++)
                acc[i][j] = __builtin_amdgcn_mfma_f32_16x16x32_bf16(aF[i], bF[j], acc[i][j], 0, 0, 0);
        __syncthreads();
    }

    // epilogue: dnorm_n scale + bias + relu, fp32 store (r0 verbatim)
    #pragma unroll
    for (int i = 0; i < 4; i++) {
        int rloc = wr * 64 + i * 16 + q * 4;
        float d0 = sDn[rloc], d1 = sDn[rloc + 1], d2 = sDn[rloc + 2], d3 = sDn[rloc + 3];
        #pragma unroll
        for (int j = 0; j < 4; j++) {
            int col = wc * 64 + j * 16 + l16;
            float bsv = sBias[col];
            f32x4 c = acc[i][j];
            float* o = out + ((size_t)b * NN + n0 + rloc) * FOUT + col;
            o[0 * FOUT] = fmaxf(fmaf(c[0], d0, bsv), 0.f);
            o[1 * FOUT] = fmaxf(fmaf(c[1], d1, bsv), 0.f);
            o[2 * FOUT] = fmaxf(fmaf(c[2], d2, bsv), 0.f);
            o[3 * FOUT] = fmaxf(fmaf(c[3], d3, bsv), 0.f);
        }
    }
}

// ---------------- k_agg_f32: r0 k_agg verbatim (ws fallback) ----------------
__global__ __launch_bounds__(256) void k_agg_f32(const float* __restrict__ adj,
                                                 const u16* __restrict__ h1t,
                                                 const float* __restrict__ dnorm,
                                                 const float* __restrict__ bias,
                                                 float* __restrict__ out) {
    __shared__ u16 As[128][40];
    __shared__ u16 Bs[128][40];
    __shared__ float sDn[128];
    __shared__ float sBias[128];

    int tid = threadIdx.x;
    int b   = blockIdx.y;
    int n0  = blockIdx.x * 128;
    int wave = tid >> 6, lane = tid & 63;
    int wr = wave >> 1, wc = wave & 1;
    int q = lane >> 4, l16 = lane & 15;

    const float* A   = adj + (size_t)b * NN * NN;
    const u16*   Bm  = h1t + (size_t)b * FOUT * NN;
    if (tid < 128) { sDn[tid] = dnorm[(size_t)b * NN + n0 + tid]; sBias[tid] = bias[tid]; }

    f32x4 acc[4][4];
    #pragma unroll
    for (int i = 0; i < 4; i++)
        #pragma unroll
        for (int j = 0; j < 4; j++) acc[i][j] = (f32x4)(0.f);

    for (int kt = 0; kt < NN; kt += 32) {
        #pragma unroll
        for (int j = 0; j < 4; j++) {
            int linear = tid + j * 256;
            int m = linear >> 3, k4 = (linear & 7) << 2;
            float4 v = *(const float4*)(A + (size_t)(n0 + m) * NN + kt + k4);
            *(ushort4*)&As[m][k4] = f2bf4(v);
        }
        #pragma unroll
        for (int j = 0; j < 2; j++) {
            int linear = tid + j * 256;
            int g = linear >> 2, k8 = (linear & 3) << 3;
            *(uint4*)&Bs[g][k8] = *(const uint4*)(Bm + (size_t)g * NN + kt + k8);
        }
        __syncthreads();
        bfrag aF[4], bF[4];
        #pragma unroll
        for (int i = 0; i < 4; i++) aF[i] = *(const bfrag*)&As[wr * 64 + i * 16 + l16][q * 8];
        #pragma unroll
        for (int j = 0; j < 4; j++) bF[j] = *(const bfrag*)&Bs[wc * 64 + j * 16 + l16][q * 8];
        #pragma unroll
        for (int i = 0; i < 4; i++)
            #pragma unroll
            for (int j = 0; j < 4; j++)
                acc[i][j] = __builtin_amdgcn_mfma_f32_16x16x32_bf16(aF[i], bF[j], acc[i][j], 0, 0, 0);
        __syncthreads();
    }

    #pragma unroll
    for (int i = 0; i < 4; i++) {
        int rloc = wr * 64 + i * 16 + q * 4;
        float d0 = sDn[rloc], d1 = sDn[rloc + 1], d2 = sDn[rloc + 2], d3 = sDn[rloc + 3];
        #pragma unroll
        for (int j = 0; j < 4; j++) {
            int col = wc * 64 + j * 16 + l16;
            float bsv = sBias[col];
            f32x4 c = acc[i][j];
            float* o = out + ((size_t)b * NN + n0 + rloc) * FOUT + col;
            o[0 * FOUT] = fmaxf(fmaf(c[0], d0, bsv), 0.f);
            o[1 * FOUT] = fmaxf(fmaf(c[1], d1, bsv), 0.f);
            o[2 * FOUT] = fmaxf(fmaf(c[2], d2, bsv), 0.f);
            o[3 * FOUT] = fmaxf(fmaf(c[3], d3, bsv), 0.f);
        }
    }
}

extern "C" void kernel_launch(void* const* d_in, const int* in_sizes, int n_in,
                              void* d_out, int out_size, void* d_ws, size_t ws_size,
                              hipStream_t stream) {
    const float* adj  = (const float*)d_in[0];
    const float* x    = (const float*)d_in[1];
    const float* W    = (const float*)d_in[2];
    const float* bias = (const float*)d_in[3];
    float* out = (float*)d_out;

    char* ws = (char*)d_ws;
    float* dnorm = (float*)ws;                                   // 65536 f32 = 256 KB
    u16*   Wt    = (u16*)(ws + 262144);                          // 16384 bf16 = 32 KB
    u16*   h1t   = (u16*)(ws + 262144 + 32768);                  // 8.4M bf16 = 16.8 MB
    u16*   adjb  = (u16*)(ws + 262144 + 32768 + 16777216);       // 33.5M bf16 = 67.1 MB

    const size_t need_fast = 262144ull + 32768ull + 16777216ull + 67108864ull;  // 84.2 MB

    hipLaunchKernelGGL(k_prep, dim3(64), dim3(256), 0, stream, W, Wt);

    if (ws_size >= need_fast) {
        hipLaunchKernelGGL(k_degcvt,  dim3(BATCH * NN / 4), dim3(256), 0, stream, adj, adjb, dnorm);
        hipLaunchKernelGGL(k_xw,      dim3(BATCH * NN / 128), dim3(256), 0, stream, x, Wt, dnorm, h1t);
        hipLaunchKernelGGL(k_agg_lds, dim3(4, BATCH), dim3(256), 0, stream, adjb, h1t, dnorm, bias, out);
    } else {
        hipLaunchKernelGGL(k_deg,     dim3(BATCH * NN / 4), dim3(256), 0, stream, adj, dnorm);
        hipLaunchKernelGGL(k_xw,      dim3(BATCH * NN / 128), dim3(256), 0, stream, x, Wt, dnorm, h1t);
        hipLaunchKernelGGL(k_agg_f32, dim3(4, BATCH), dim3(256), 0, stream, adj, h1t, dnorm, bias, out);
    }
}

// Round 8
// 245.122 us; speedup vs baseline: 1.0799x; 1.0799x over previous
//
#include <hip/hip_runtime.h>
#include <hip/hip_bf16.h>
#include <cstdint>

// GCN layer: y = relu(dnorm_n * (adj @ (dnorm_m * x @ W)) + b)
// B=128, N=512, F_IN=F_OUT=128, fp32 in/out. bf16 MFMA internally.
//
// v9 = v7 fused structure + drain-free raw barriers + XOR-swizzled LDS.
//   Every barrier in k_fused is lgkmcnt(0)+s_barrier (NO vmcnt drain) so
//   register-staged global loads fly across barriers (the compiler's
//   vmcnt(0)-before-__syncthreads drain was the documented stall).
//   Numerics bit-identical to v5/v6/v7: same values, same MFMA order.

#define BATCH 128
#define NN    512
#define FIN   128
#define FOUT  128

typedef unsigned short u16;
typedef __attribute__((ext_vector_type(8))) __bf16 bfrag;   // 8 bf16 = 4 VGPRs
typedef __attribute__((ext_vector_type(4))) float  f32x4;

__device__ __forceinline__ u16 f2bf(float f) {
    uint32_t u = __builtin_bit_cast(uint32_t, f);
    u += 0x7fffu + ((u >> 16) & 1u);          // round-nearest-even
    return (u16)(u >> 16);
}
__device__ __forceinline__ ushort4 f2bf4(float4 v) {
    ushort4 r;
    r.x = f2bf(v.x); r.y = f2bf(v.y); r.z = f2bf(v.z); r.w = f2bf(v.w);
    return r;
}

// drain-free barrier primitives (loads to registers need no vmcnt at barrier)
__device__ __forceinline__ void bar_publish() {   // own ds_writes -> visible
    asm volatile("s_waitcnt lgkmcnt(0)" ::: "memory");
    __builtin_amdgcn_s_barrier();
    asm volatile("" ::: "memory");
}
__device__ __forceinline__ void bar_only() {      // pure rendezvous
    asm volatile("" ::: "memory");
    __builtin_amdgcn_s_barrier();
    asm volatile("" ::: "memory");
}

// ---------------- k_prep: Wt[g][k] = bf16(W[k][g]) --------------------------
__global__ __launch_bounds__(256) void k_prep(const float* __restrict__ W,
                                              u16* __restrict__ Wt) {
    int idx = blockIdx.x * 256 + threadIdx.x;   // grid 64 -> 16384 elements
    int g = idx >> 7, k = idx & 127;
    Wt[idx] = f2bf(W[k * FOUT + g]);
}

// ---------------- k_deg: dnorm[row] = rsqrt(rowsum(adj)) --------------------
__global__ __launch_bounds__(256) void k_deg(const float* __restrict__ adj,
                                             float* __restrict__ dnorm) {
    int wave = threadIdx.x >> 6;
    int lane = threadIdx.x & 63;
    int row  = (blockIdx.x << 2) + wave;          // [0, B*N)
    const float4* p = (const float4*)(adj + (size_t)row * NN);
    float4 v0 = p[lane];
    float4 v1 = p[lane + 64];
    float s = v0.x + v0.y + v0.z + v0.w + v1.x + v1.y + v1.z + v1.w;
    #pragma unroll
    for (int off = 32; off > 0; off >>= 1) s += __shfl_down(s, off, 64);
    if (lane == 0) dnorm[row] = (s > 0.f) ? rsqrtf(s) : 0.f;
}

// ---------------- k_fused: h1 in LDS, then aggregate ------------------------
// blockIdx = (half, b). 512 threads = 8 waves. LDS ~146.5 KiB -> 1 block/CU.
// hs      : logical h1t[g][m], phys col = m ^ ((g&7)<<3)       (bank-free)
// stage   : 16 KiB buffer shared by phase-1 A-tile (logical [128][64],
//           phys col = k ^ ((m&7)<<3)) and phase-2 A-tile (logical [256][32]
//           packed as [128][64]: phys col = (((r&1)<<5)|c) ^ (((r>>1)&7)<<3))
__global__ __launch_bounds__(512) void k_fused(const float* __restrict__ x,
                                               const u16* __restrict__ Wt,
                                               const float* __restrict__ adj,
                                               const float* __restrict__ dnorm,
                                               const float* __restrict__ bias,
                                               float* __restrict__ out) {
    __shared__ __align__(16) u16 hs[128][512];     // 128 KiB
    __shared__ __align__(16) u16 stage[128][64];   // 16 KiB
    __shared__ float sDn[512];
    __shared__ float sBias[128];

    int tid  = threadIdx.x;               // 0..511
    int b    = blockIdx.y;
    int n0   = blockIdx.x * 256;          // out-row base (0 or 256)
    int wave = tid >> 6, lane = tid & 63;
    int q = lane >> 4, l16 = lane & 15;

    sDn[tid] = dnorm[(size_t)b * NN + tid];
    if (tid < 128) sBias[tid] = bias[tid];
    // (published by the first bar_publish below)

    // -------- phase-2 prologue loads issued NOW: ~whole phase 1 to land -----
    float4 lda[4], ldb[4];
    #pragma unroll
    for (int jj = 0; jj < 4; jj++) {
        int linear = tid + jj * 512;             // 0..2047
        int m = linear >> 3, k4 = (linear & 7) << 2;
        lda[jj] = *(const float4*)(adj + ((size_t)b * NN + n0 + m) * NN + 0 + k4);
        ldb[jj] = *(const float4*)(adj + ((size_t)b * NN + n0 + m) * NN + 32 + k4);
    }

    // ---------------- phase 1: h1[b] -> hs ----------------
    {
        int wr1 = wave >> 2;              // 0..1  (64-row group)
        int wc1 = wave & 3;               // 0..3  (32-col group)

        bfrag wreg[4][2];
        #pragma unroll
        for (int kt4 = 0; kt4 < 4; kt4++)
            #pragma unroll
            for (int j = 0; j < 2; j++) {
                int g = wc1 * 32 + j * 16 + l16;
                wreg[kt4][j] = *(const bfrag*)(Wt + (size_t)g * FIN + kt4 * 32 + q * 8);
            }

        // 1-deep prefetch across the 8 (chunk,half) stages
        float4 xld[4];
        #pragma unroll
        for (int jj = 0; jj < 4; jj++) {          // stage 0: c=0, kh=0
            int linear = tid + jj * 512;
            int m = linear >> 4, k4 = (linear & 15) << 2;
            xld[jj] = *(const float4*)(x + ((size_t)b * NN + 0 + m) * FIN + 0 + k4);
        }

        for (int c = 0; c < 4; c++) {
            int m0 = c * 128;
            f32x4 acc2[4][2];
            #pragma unroll
            for (int i = 0; i < 4; i++)
                #pragma unroll
                for (int j = 0; j < 2; j++) acc2[i][j] = (f32x4)(0.f);

            for (int kh = 0; kh < 2; kh++) {
                // write current stage from regs (XOR-swizzled cols)
                #pragma unroll
                for (int jj = 0; jj < 4; jj++) {
                    int linear = tid + jj * 512;         // 0..2047
                    int m = linear >> 4, k4 = (linear & 15) << 2;
                    *(ushort4*)&stage[m][k4 ^ ((m & 7) << 3)] = f2bf4(xld[jj]);
                }
                bar_publish();
                // issue next stage's loads (fly across the raw barriers)
                int s = c * 2 + kh + 1;                  // next stage index
                if (s < 8) {
                    int cn = s >> 1, khn = s & 1;
                    #pragma unroll
                    for (int jj = 0; jj < 4; jj++) {
                        int linear = tid + jj * 512;
                        int m = linear >> 4, k4 = (linear & 15) << 2;
                        xld[jj] = *(const float4*)(x + ((size_t)b * NN + cn * 128 + m) * FIN + khn * 64 + k4);
                    }
                }
                #pragma unroll
                for (int kt2 = 0; kt2 < 2; kt2++) {
                    int kt4 = kh * 2 + kt2;              // accumulation order 0,1,2,3
                    bfrag aF[4];
                    #pragma unroll
                    for (int i = 0; i < 4; i++) {
                        int r = wr1 * 64 + i * 16 + l16;
                        aF[i] = *(const bfrag*)&stage[r][(kt2 * 32 + q * 8) ^ ((r & 7) << 3)];
                    }
                    #pragma unroll
                    for (int i = 0; i < 4; i++)
                        #pragma unroll
                        for (int j = 0; j < 2; j++)
                            acc2[i][j] = __builtin_amdgcn_mfma_f32_16x16x32_bf16(aF[i], wreg[kt4][j], acc2[i][j], 0, 0, 0);
                }
                bar_only();   // stage-buf reads consumed; safe to overwrite next
            }
            // epilogue: Dm scale + round, store hs[g][m] (XOR-swizzled)
            #pragma unroll
            for (int i = 0; i < 4; i++) {
                int mb = m0 + wr1 * 64 + i * 16 + q * 4;
                float d0 = sDn[mb], d1 = sDn[mb + 1], d2 = sDn[mb + 2], d3 = sDn[mb + 3];
                #pragma unroll
                for (int j = 0; j < 2; j++) {
                    int g = wc1 * 32 + j * 16 + l16;
                    f32x4 cc = acc2[i][j];
                    ushort4 v;
                    v.x = f2bf(cc[0] * d0); v.y = f2bf(cc[1] * d1);
                    v.z = f2bf(cc[2] * d2); v.w = f2bf(cc[3] * d3);
                    *(ushort4*)&hs[g][mb ^ ((g & 7) << 3)] = v;
                }
            }
        }
    }
    bar_publish();   // hs complete & visible; stage buffer free

    // ---------------- phase 2: out = relu(Dn * (adj @ hs) + b) --------------
    {
        int wr = wave >> 1;               // 0..3  (64-row group of 256)
        int wc = wave & 1;                // 0..1  (64-col group)
        f32x4 acc[4][4];
        #pragma unroll
        for (int i = 0; i < 4; i++)
            #pragma unroll
            for (int j = 0; j < 4; j++) acc[i][j] = (f32x4)(0.f);

        for (int kt2 = 0; kt2 < NN; kt2 += 64) {
            // ---- sub-step A: kt = kt2 (data in lda) ----
            #pragma unroll
            for (int jj = 0; jj < 4; jj++) {
                int linear = tid + jj * 512;
                int r = linear >> 3, c4 = (linear & 7) << 2;
                *(ushort4*)&stage[r >> 1][((((r & 1) << 5) | c4)) ^ (((r >> 1) & 7) << 3)] = f2bf4(lda[jj]);
            }
            bar_publish();
            if (kt2 + 64 < NN) {                     // refill lda <- kt2+64
                #pragma unroll
                for (int jj = 0; jj < 4; jj++) {
                    int linear = tid + jj * 512;
                    int m = linear >> 3, k4 = (linear & 7) << 2;
                    lda[jj] = *(const float4*)(adj + ((size_t)b * NN + n0 + m) * NN + kt2 + 64 + k4);
                }
            }
            {
                bfrag aF[4], bF[4];
                #pragma unroll
                for (int i = 0; i < 4; i++) {
                    int r = wr * 64 + i * 16 + l16;
                    aF[i] = *(const bfrag*)&stage[r >> 1][((((r & 1) << 5) | (q * 8))) ^ (((r >> 1) & 7) << 3)];
                }
                #pragma unroll
                for (int j = 0; j < 4; j++) {
                    int g = wc * 64 + j * 16 + l16;
                    bF[j] = *(const bfrag*)&hs[g][(kt2 + q * 8) ^ ((g & 7) << 3)];
                }
                #pragma unroll
                for (int i = 0; i < 4; i++)
                    #pragma unroll
                    for (int j = 0; j < 4; j++)
                        acc[i][j] = __builtin_amdgcn_mfma_f32_16x16x32_bf16(aF[i], bF[j], acc[i][j], 0, 0, 0);
            }
            bar_only();

            // ---- sub-step B: kt = kt2 + 32 (data in ldb) ----
            #pragma unroll
            for (int jj = 0; jj < 4; jj++) {
                int linear = tid + jj * 512;
                int r = linear >> 3, c4 = (linear & 7) << 2;
                *(ushort4*)&stage[r >> 1][((((r & 1) << 5) | c4)) ^ (((r >> 1) & 7) << 3)] = f2bf4(ldb[jj]);
            }
            bar_publish();
            if (kt2 + 96 < NN) {                     // refill ldb <- kt2+96
                #pragma unroll
                for (int jj = 0; jj < 4; jj++) {
                    int linear = tid + jj * 512;
                    int m = linear >> 3, k4 = (linear & 7) << 2;
                    ldb[jj] = *(const float4*)(adj + ((size_t)b * NN + n0 + m) * NN + kt2 + 96 + k4);
                }
            }
            {
                bfrag aF[4], bF[4];
                #pragma unroll
                for (int i = 0; i < 4; i++) {
                    int r = wr * 64 + i * 16 + l16;
                    aF[i] = *(const bfrag*)&stage[r >> 1][((((r & 1) << 5) | (q * 8))) ^ (((r >> 1) & 7) << 3)];
                }
                #pragma unroll
                for (int j = 0; j < 4; j++) {
                    int g = wc * 64 + j * 16 + l16;
                    bF[j] = *(const bfrag*)&hs[g][(kt2 + 32 + q * 8) ^ ((g & 7) << 3)];
                }
                #pragma unroll
                for (int i = 0; i < 4; i++)
                    #pragma unroll
                    for (int j = 0; j < 4; j++)
                        acc[i][j] = __builtin_amdgcn_mfma_f32_16x16x32_bf16(aF[i], bF[j], acc[i][j], 0, 0, 0);
            }
            bar_only();
        }

        // epilogue: Dn scale + bias + relu, fp32 store
        #pragma unroll
        for (int i = 0; i < 4; i++) {
            int rloc = wr * 64 + i * 16 + q * 4;
            float d0 = sDn[n0 + rloc],     d1 = sDn[n0 + rloc + 1];
            float d2 = sDn[n0 + rloc + 2], d3 = sDn[n0 + rloc + 3];
            #pragma unroll
            for (int j = 0; j < 4; j++) {
                int col = wc * 64 + j * 16 + l16;
                float bsv = sBias[col];
                f32x4 c = acc[i][j];
                float* o = out + ((size_t)b * NN + n0 + rloc) * FOUT + col;
                o[0 * FOUT] = fmaxf(fmaf(c[0], d0, bsv), 0.f);
                o[1 * FOUT] = fmaxf(fmaf(c[1], d1, bsv), 0.f);
                o[2 * FOUT] = fmaxf(fmaf(c[2], d2, bsv), 0.f);
                o[3 * FOUT] = fmaxf(fmaf(c[3], d3, bsv), 0.f);
            }
        }
    }
}

extern "C" void kernel_launch(void* const* d_in, const int* in_sizes, int n_in,
                              void* d_out, int out_size, void* d_ws, size_t ws_size,
                              hipStream_t stream) {
    const float* adj  = (const float*)d_in[0];
    const float* x    = (const float*)d_in[1];
    const float* W    = (const float*)d_in[2];
    const float* bias = (const float*)d_in[3];
    float* out = (float*)d_out;

    char* ws = (char*)d_ws;
    float* dnorm = (float*)ws;                                   // 65536 f32 = 256 KB
    u16*   Wt    = (u16*)(ws + 262144);                          // 16384 bf16 = 32 KB

    hipLaunchKernelGGL(k_prep,  dim3(64), dim3(256), 0, stream, W, Wt);
    hipLaunchKernelGGL(k_deg,   dim3(BATCH * NN / 4), dim3(256), 0, stream, adj, dnorm);
    hipLaunchKernelGGL(k_fused, dim3(2, BATCH), dim3(512), 0, stream,
                       x, Wt, adj, dnorm, bias, out);
}